// Round 13
// baseline (254.171 us; speedup 1.0000x reference)
//
#include <hip/hip_runtime.h>

// GCN 2-layer on MI355X — Round 13: Round 12 with corrected agg grid size
// (the R12 launch covered only 1/8 of nodes: gB double-divided by 8).
//
// g[j] = x[j]*dinv[j].  layer1: hs2 via relu(dinv*(sum g)+b1)@W2*dinv
// layer2: out[i] = dinv[i]*(sum hs2[src]+hs2[i]) + b2
//
// sortA: 8192 edges/block. Phase1: per-wave LDS hist over dp=dst>>11;
//   one global atomicAdd per (block,dp) reserves space; per-wave cursors.
//   Phase2: place packed=(ld<<18)|src via wave-private LDS cursors.
// localC: block=(dp,b), b<8: in-place LDS counting sort of its eighth ->
//   srcsorted + runStart[(dp*8+b)*2049+ld].
// agg: wave lane = (node&7)|(b<<3): 8 consecutive nodes x 8 runs; coalesced
//   runStart loads + contiguous srcsorted streams; shfl_xor 8/16/32 combine.
//   Block = 512 threads = 8 waves = 64 nodes -> grid = ceil(n/64) = 3125.

#define EPB   8192   // edges per sortA block
#define PART  2048   // nodes per partition
#define LPBIT 11
#define SRCB  18     // src bits in packed
#define BC    8      // localC sub-blocks per dp (= runs per node)
#define RSTR  2049   // runStart stride per (dp,b)
#define CAP   69632  // words per dp region (mean 65306 + ~17 sigma)
#define STCAP 8704   // localC stage words (CAP/8)
#define WV    8      // waves per 512-thread block

// ---------------- sortA: fused count + reserve + scatter ----------------

__global__ __launch_bounds__(512) void sortA_kernel(
    const int* __restrict__ src, const int* __restrict__ dst,
    int* __restrict__ cursor, unsigned* __restrict__ packed, int E, int P) {
    __shared__ int cnt[WV * 128];   // per-wave phase1 counts
    __shared__ int wcur[WV * 128];  // per-wave phase2 absolute cursors
    int tid = threadIdx.x;
    int wid = tid >> 6;
    for (int k = tid; k < WV * 128; k += 512) cnt[k] = 0;
    __syncthreads();
    int nv4 = E >> 2;
    int b4 = (blockIdx.x * EPB) >> 2;
    int e4 = min(b4 + (EPB >> 2), nv4);
    const int4* d4 = (const int4*)dst;
    const int4* s4 = (const int4*)src;
    int* mycnt = cnt + wid * 128;
    #pragma unroll
    for (int k = 0; k < (EPB >> 2); k += 512) {
        int i = b4 + k + tid;
        if (i < e4) {
            int4 d = d4[i];
            atomicAdd(&mycnt[d.x >> LPBIT], 1);
            atomicAdd(&mycnt[d.y >> LPBIT], 1);
            atomicAdd(&mycnt[d.z >> LPBIT], 1);
            atomicAdd(&mycnt[d.w >> LPBIT], 1);
        }
    }
    bool lastblk = (blockIdx.x == gridDim.x - 1);
    if (lastblk) {  // scalar tail (E % 4)
        int e = (nv4 << 2) + tid;
        if (e < E) atomicAdd(&mycnt[dst[e] >> LPBIT], 1);
    }
    __syncthreads();
    if (tid < 128) {  // tid = dp
        int c[WV];
        int tot = 0;
        #pragma unroll
        for (int w = 0; w < WV; w++) { c[w] = cnt[w * 128 + tid]; tot += c[w]; }
        int base = (tot > 0) ? atomicAdd(&cursor[tid], tot) : 0;
        int run = tid * CAP + base;
        #pragma unroll
        for (int w = 0; w < WV; w++) { wcur[w * 128 + tid] = run; run += c[w]; }
    }
    __syncthreads();
    int* mycur = wcur + wid * 128;
    #pragma unroll
    for (int k = 0; k < (EPB >> 2); k += 512) {
        int i = b4 + k + tid;
        if (i < e4) {
            int4 d = d4[i];   // L2-hot re-read
            int4 sv = s4[i];
            int p0 = atomicAdd(&mycur[d.x >> LPBIT], 1);
            packed[p0] = ((unsigned)(d.x & (PART - 1)) << SRCB) | (unsigned)sv.x;
            int p1 = atomicAdd(&mycur[d.y >> LPBIT], 1);
            packed[p1] = ((unsigned)(d.y & (PART - 1)) << SRCB) | (unsigned)sv.y;
            int p2 = atomicAdd(&mycur[d.z >> LPBIT], 1);
            packed[p2] = ((unsigned)(d.z & (PART - 1)) << SRCB) | (unsigned)sv.z;
            int p3 = atomicAdd(&mycur[d.w >> LPBIT], 1);
            packed[p3] = ((unsigned)(d.w & (PART - 1)) << SRCB) | (unsigned)sv.w;
        }
    }
    if (lastblk) {
        int e = (nv4 << 2) + tid;
        if (e < E) {
            int d = dst[e];
            int pos = atomicAdd(&mycur[d >> LPBIT], 1);
            packed[pos] = ((unsigned)(d & (PART - 1)) << SRCB) | (unsigned)src[e];
        }
    }
}

// ---------------- localC: in-place LDS counting sort per eighth ----------

__global__ __launch_bounds__(512) void localC_kernel(
    const unsigned* __restrict__ packed, const int* __restrict__ cursor,
    int* __restrict__ runStart, int* __restrict__ srcsorted) {
    __shared__ int hist[PART];      // counts -> absolute cursors
    __shared__ int sdata[512];
    __shared__ unsigned stage[STCAP];
    int tid = threadIdx.x;
    int dp = blockIdx.x >> 3, b = blockIdx.x & (BC - 1);
    int dpbase = dp * CAP;
    int tot = cursor[dp];
    int lo = dpbase + (int)(((long long)tot * b) / BC);
    int hi = dpbase + (int)(((long long)tot * (b + 1)) / BC);
    for (int k = tid; k < PART; k += 512) hist[k] = 0;
    __syncthreads();
    for (int i = lo + tid; i < hi; i += 512)
        atomicAdd(&hist[packed[i] >> SRCB], 1);
    __syncthreads();
    // exclusive scan of hist[2048], 4 elems/thread
    int off = tid * 4;
    int v0 = hist[off], v1 = hist[off + 1], v2 = hist[off + 2], v3 = hist[off + 3];
    int s = v0 + v1 + v2 + v3;
    int x = s;
    sdata[tid] = x;
    __syncthreads();
    for (int o = 1; o < 512; o <<= 1) {
        int t = (tid >= o) ? sdata[tid - o] : 0;
        __syncthreads();
        x += t;
        sdata[tid] = x;
        __syncthreads();
    }
    int run = x - s;
    int* rs = runStart + (size_t)(dp * BC + b) * RSTR;
    int c0 = lo + run, c1 = c0 + v0, c2 = c1 + v1, c3 = c2 + v2;
    rs[off] = c0; rs[off + 1] = c1; rs[off + 2] = c2; rs[off + 3] = c3;
    __syncthreads();
    hist[off] = c0; hist[off + 1] = c1; hist[off + 2] = c2; hist[off + 3] = c3;
    if (tid == 0) rs[PART] = hi;  // end sentinel
    __syncthreads();
    int total = hi - lo;
    bool ovf = total > STCAP;
    for (int i = lo + tid; i < hi; i += 512) {
        unsigned w = packed[i];
        int pos = atomicAdd(&hist[w >> SRCB], 1);
        unsigned sv = w & ((1u << SRCB) - 1);
        if (!ovf) stage[pos - lo] = sv;
        else srcsorted[pos] = sv;
    }
    __syncthreads();
    if (!ovf)
        for (int j = tid; j < total; j += 512) srcsorted[lo + j] = (int)stage[j];
}

// ---------------- Node-side (atomic-free, wave-coalesced) ----------------
// Wave lane = (node&7) | (b<<3): 8 consecutive nodes x 8 runs per wave.
// Block = 8 waves = 64 nodes; grid = ceil(n/64).

__global__ __launch_bounds__(512) void dinvg_kernel(
    const int* __restrict__ runStart, const float* __restrict__ x,
    float* __restrict__ dinv, float* __restrict__ g, int n) {
    int t = blockIdx.x * 512 + threadIdx.x;
    int lane = threadIdx.x & 63;
    int node = (t >> 6) * 8 + (lane & 7);
    int b = lane >> 3;
    int deg = 0;
    if (node < n) {
        int dp = node >> LPBIT, ld = node & (PART - 1);
        const int* rs = runStart + (size_t)(dp * BC + b) * RSTR + ld;
        deg = rs[1] - rs[0];
    }
    deg += __shfl_xor(deg, 8);
    deg += __shfl_xor(deg, 16);
    deg += __shfl_xor(deg, 32);
    if (node < n && b == 0) {
        float d = rsqrtf((float)deg + 1.0f);  // +1 self-loop
        dinv[node] = d;
        float2 xv = ((const float2*)x)[node];
        ((float2*)g)[node] = make_float2(xv.x * d, xv.y * d);
    }
}

__global__ __launch_bounds__(512) void agg1_kernel(
    const int* __restrict__ runStart, const int* __restrict__ srcsorted,
    const float* __restrict__ g, const float* __restrict__ dinv,
    const float* __restrict__ W1, const float* __restrict__ b1,
    const float* __restrict__ W2, float* __restrict__ hs2, int n) {
    int t = blockIdx.x * 512 + threadIdx.x;
    int lane = threadIdx.x & 63;
    int node = (t >> 6) * 8 + (lane & 7);
    int b = lane >> 3;
    const float2* gp = (const float2*)g;
    float s0 = 0.0f, s1 = 0.0f;
    if (node < n) {
        int dp = node >> LPBIT, ld = node & (PART - 1);
        const int* rs = runStart + (size_t)(dp * BC + b) * RSTR + ld;
        int p0 = rs[0], p1 = rs[1];
        int p = p0;
        for (; p + 4 <= p1; p += 4) {
            int a = srcsorted[p], bb = srcsorted[p + 1];
            int c = srcsorted[p + 2], e = srcsorted[p + 3];
            float2 w0 = gp[a], w1 = gp[bb], w2 = gp[c], w3 = gp[e];
            s0 += w0.x + w1.x + w2.x + w3.x;
            s1 += w0.y + w1.y + w2.y + w3.y;
        }
        for (; p < p1; p++) {
            float2 w = gp[srcsorted[p]];
            s0 += w.x;
            s1 += w.y;
        }
    }
    s0 += __shfl_xor(s0, 8);  s1 += __shfl_xor(s1, 8);
    s0 += __shfl_xor(s0, 16); s1 += __shfl_xor(s1, 16);
    s0 += __shfl_xor(s0, 32); s1 += __shfl_xor(s1, 32);
    if (node < n && b == 0) {
        float d = dinv[node];
        float2 gi = gp[node];
        s0 = (s0 + gi.x) * d;
        s1 = (s1 + gi.y) * d;
        float h[8];
        #pragma unroll
        for (int f = 0; f < 8; f++)
            h[f] = fmaxf(s0 * W1[f] + s1 * W1[8 + f] + b1[f], 0.0f);
        float oc[4];
        #pragma unroll
        for (int k = 0; k < 4; k++) {
            float a = 0.0f;
            #pragma unroll
            for (int f = 0; f < 8; f++) a += h[f] * W2[4 * f + k];
            oc[k] = a * d;
        }
        float4 o;
        o.x = oc[0]; o.y = oc[1]; o.z = oc[2]; o.w = oc[3];
        *(float4*)(hs2 + 4 * (size_t)node) = o;
    }
}

__global__ __launch_bounds__(512) void agg2_kernel(
    const int* __restrict__ runStart, const int* __restrict__ srcsorted,
    const float* __restrict__ hs2, const float* __restrict__ dinv,
    const float* __restrict__ b2, float* __restrict__ out, int n) {
    int t = blockIdx.x * 512 + threadIdx.x;
    int lane = threadIdx.x & 63;
    int node = (t >> 6) * 8 + (lane & 7);
    int b = lane >> 3;
    const float4* hp = (const float4*)hs2;
    float s0 = 0.0f, s1 = 0.0f, s2 = 0.0f, s3 = 0.0f;
    if (node < n) {
        int dp = node >> LPBIT, ld = node & (PART - 1);
        const int* rs = runStart + (size_t)(dp * BC + b) * RSTR + ld;
        int p0 = rs[0], p1 = rs[1];
        int p = p0;
        for (; p + 4 <= p1; p += 4) {
            int a = srcsorted[p], bb = srcsorted[p + 1];
            int c = srcsorted[p + 2], e = srcsorted[p + 3];
            float4 w0 = hp[a], w1 = hp[bb], w2 = hp[c], w3 = hp[e];
            s0 += w0.x + w1.x + w2.x + w3.x;
            s1 += w0.y + w1.y + w2.y + w3.y;
            s2 += w0.z + w1.z + w2.z + w3.z;
            s3 += w0.w + w1.w + w2.w + w3.w;
        }
        for (; p < p1; p++) {
            float4 w = hp[srcsorted[p]];
            s0 += w.x; s1 += w.y; s2 += w.z; s3 += w.w;
        }
    }
    s0 += __shfl_xor(s0, 8);  s1 += __shfl_xor(s1, 8);
    s2 += __shfl_xor(s2, 8);  s3 += __shfl_xor(s3, 8);
    s0 += __shfl_xor(s0, 16); s1 += __shfl_xor(s1, 16);
    s2 += __shfl_xor(s2, 16); s3 += __shfl_xor(s3, 16);
    s0 += __shfl_xor(s0, 32); s1 += __shfl_xor(s1, 32);
    s2 += __shfl_xor(s2, 32); s3 += __shfl_xor(s3, 32);
    if (node < n && b == 0) {
        float d = dinv[node];
        float4 hi2 = hp[node];
        float4 o;
        o.x = d * (s0 + hi2.x) + b2[0];
        o.y = d * (s1 + hi2.y) + b2[1];
        o.z = d * (s2 + hi2.z) + b2[2];
        o.w = d * (s3 + hi2.w) + b2[3];
        *(float4*)(out + 4 * (size_t)node) = o;
    }
}

extern "C" void kernel_launch(void* const* d_in, const int* in_sizes, int n_in,
                              void* d_out, int out_size, void* d_ws, size_t ws_size,
                              hipStream_t stream) {
    const float* x   = (const float*)d_in[0];
    const int*   ei  = (const int*)d_in[1];
    const float* W1  = (const float*)d_in[2];
    const float* b1  = (const float*)d_in[3];
    const float* W2  = (const float*)d_in[4];
    const float* b2  = (const float*)d_in[5];
    float* out = (float*)d_out;

    const int n = in_sizes[0] / 2;  // x is [N,2]
    const int E = in_sizes[1] / 2;  // edge_index is [2,E]
    const int* src = ei;
    const int* dst = ei + E;

    const int P  = (n + PART - 1) >> LPBIT;  // 98
    const int B1 = (E + EPB - 1) / EPB;      // 782

    int* ws = (int*)d_ws;
    int* cursor = ws;                                        // 128
    int* runStart = ws + 128;                                // P*BC*RSTR
    size_t rssz = (((size_t)P * BC * RSTR) + 3) & ~(size_t)3;
    unsigned* packed = (unsigned*)(runStart + rssz);         // P*CAP
    int* srcsorted = (int*)(packed + (size_t)P * CAP);       // P*CAP
    // packed region dead after localC; overlay node buffers (7*nd << P*CAP):
    size_t nd = (size_t)P << LPBIT;                          // 200704
    float* dinv = (float*)packed;                            // nd
    float* g    = dinv + nd;                                 // 2*nd
    float* hs2  = g + 2 * nd;                                // 4*nd

    hipMemsetAsync(cursor, 0, 128 * sizeof(int), stream);

    // Block = 512 threads = 8 waves x 8 nodes = 64 nodes per block.
    const int gB = (n + 63) / 64;  // 3125

    sortA_kernel <<<B1, 512, 0, stream>>>(src, dst, cursor, packed, E, P);
    localC_kernel<<<P * BC, 512, 0, stream>>>(packed, cursor, runStart, srcsorted);
    dinvg_kernel <<<gB, 512, 0, stream>>>(runStart, x, dinv, g, n);
    agg1_kernel  <<<gB, 512, 0, stream>>>(runStart, srcsorted, g, dinv, W1, b1, W2, hs2, n);
    agg2_kernel  <<<gB, 512, 0, stream>>>(runStart, srcsorted, hs2, dinv, b2, out, n);
}

// Round 14
// 247.603 us; speedup vs baseline: 1.0265x; 1.0265x over previous
//
#include <hip/hip_runtime.h>

// GCN 2-layer on MI355X — Round 14: best-measured phases recombined.
// sortA (block-shared cursors + register-stashed edges, single global read)
// + localC BC=4 (R10 config) + thread-per-node agg (R10 config).
//
// g[j] = x[j]*dinv[j].  layer1: hs2 via relu(dinv*(sum g)+b1)@W2*dinv
// layer2: out[i] = dinv[i]*(sum hs2[src]+hs2[i]) + b2
//
// sortA: 8192 edges/block, 16 edges/thread stashed in registers. Phase1
//   LDS hist over dp=dst>>11 (128 counters); one global atomicAdd per
//   (block,dp) reserves space in dp's CAP region; phase2 places
//   packed=(ld<<18)|src from registers via block-shared LDS cursors.
// localC: block=(dp,b), b<4: in-place LDS counting sort of its quarter ->
//   srcsorted + runStart[(dp*4+b)*2049+ld].
// agg: thread = node, 4 runs, register acc, fused dense epilogues.
//
// ws: cursor[128] | runStart[98*4*2049] | packed[98*CAP] | srcsorted[98*CAP]
//     (dinv|g|hs2 overlay packed after localC)   ~56 MB

#define EPB   8192   // edges per sortA block
#define PART  2048   // nodes per partition
#define LPBIT 11
#define SRCB  18     // src bits in packed
#define BC    4      // localC sub-blocks per dp (= runs per node)
#define RSTR  2049   // runStart stride per (dp,b)
#define CAP   69632  // words per dp region (mean 65306 + ~17 sigma)
#define STCAP 17408  // localC stage words (CAP/4)

// ---------------- sortA: fused count + reserve + scatter ----------------

__global__ __launch_bounds__(512) void sortA_kernel(
    const int* __restrict__ src, const int* __restrict__ dst,
    int* __restrict__ cursor, unsigned* __restrict__ packed, int E, int P) {
    __shared__ int cnt[128];   // phase1 counts -> phase2 absolute cursors
    int tid = threadIdx.x;
    if (tid < 128) cnt[tid] = 0;
    __syncthreads();
    int nv4 = E >> 2;
    int b4 = (blockIdx.x * EPB) >> 2;
    const int4* d4 = (const int4*)dst;
    const int4* s4 = (const int4*)src;
    // Phase 1: load 4 int4 pairs into registers, histogram dp.
    int4 dv[4], sv[4];
    bool inb[4];
    #pragma unroll
    for (int k = 0; k < 4; k++) {
        int i = b4 + k * 512 + tid;
        inb[k] = (i < nv4);
        if (inb[k]) {
            dv[k] = d4[i];
            sv[k] = s4[i];
            atomicAdd(&cnt[dv[k].x >> LPBIT], 1);
            atomicAdd(&cnt[dv[k].y >> LPBIT], 1);
            atomicAdd(&cnt[dv[k].z >> LPBIT], 1);
            atomicAdd(&cnt[dv[k].w >> LPBIT], 1);
        }
    }
    bool lastblk = (blockIdx.x == gridDim.x - 1);
    int tsrc = 0, tdst = 0;
    bool tin = false;
    if (lastblk) {  // scalar tail (E % 4)
        int e = (nv4 << 2) + tid;
        tin = (e < E);
        if (tin) {
            tdst = dst[e];
            tsrc = src[e];
            atomicAdd(&cnt[tdst >> LPBIT], 1);
        }
    }
    __syncthreads();
    if (tid < 128) {
        int c = cnt[tid];
        int base = (c > 0) ? atomicAdd(&cursor[tid], c) : 0;
        cnt[tid] = tid * CAP + base;  // absolute cursor
    }
    __syncthreads();
    // Phase 2: place from registers.
    #pragma unroll
    for (int k = 0; k < 4; k++) {
        if (inb[k]) {
            int4 d = dv[k];
            int4 s = sv[k];
            int p0 = atomicAdd(&cnt[d.x >> LPBIT], 1);
            packed[p0] = ((unsigned)(d.x & (PART - 1)) << SRCB) | (unsigned)s.x;
            int p1 = atomicAdd(&cnt[d.y >> LPBIT], 1);
            packed[p1] = ((unsigned)(d.y & (PART - 1)) << SRCB) | (unsigned)s.y;
            int p2 = atomicAdd(&cnt[d.z >> LPBIT], 1);
            packed[p2] = ((unsigned)(d.z & (PART - 1)) << SRCB) | (unsigned)s.z;
            int p3 = atomicAdd(&cnt[d.w >> LPBIT], 1);
            packed[p3] = ((unsigned)(d.w & (PART - 1)) << SRCB) | (unsigned)s.w;
        }
    }
    if (tin) {
        int pos = atomicAdd(&cnt[tdst >> LPBIT], 1);
        packed[pos] = ((unsigned)(tdst & (PART - 1)) << SRCB) | (unsigned)tsrc;
    }
}

// ---------------- localC: in-place LDS counting sort per quarter ----------

__global__ __launch_bounds__(512) void localC_kernel(
    const unsigned* __restrict__ packed, const int* __restrict__ cursor,
    int* __restrict__ runStart, int* __restrict__ srcsorted) {
    __shared__ int hist[PART];      // counts -> absolute cursors
    __shared__ int sdata[512];
    __shared__ unsigned stage[STCAP];
    int tid = threadIdx.x;
    int dp = blockIdx.x >> 2, b = blockIdx.x & (BC - 1);
    int dpbase = dp * CAP;
    int tot = cursor[dp];
    int lo = dpbase + (int)(((long long)tot * b) / BC);
    int hi = dpbase + (int)(((long long)tot * (b + 1)) / BC);
    for (int k = tid; k < PART; k += 512) hist[k] = 0;
    __syncthreads();
    for (int i = lo + tid; i < hi; i += 512)
        atomicAdd(&hist[packed[i] >> SRCB], 1);
    __syncthreads();
    // exclusive scan of hist[2048], 4 elems/thread
    int off = tid * 4;
    int v0 = hist[off], v1 = hist[off + 1], v2 = hist[off + 2], v3 = hist[off + 3];
    int s = v0 + v1 + v2 + v3;
    int x = s;
    sdata[tid] = x;
    __syncthreads();
    for (int o = 1; o < 512; o <<= 1) {
        int t = (tid >= o) ? sdata[tid - o] : 0;
        __syncthreads();
        x += t;
        sdata[tid] = x;
        __syncthreads();
    }
    int run = x - s;
    int* rs = runStart + (size_t)(dp * BC + b) * RSTR;
    int c0 = lo + run, c1 = c0 + v0, c2 = c1 + v1, c3 = c2 + v2;
    rs[off] = c0; rs[off + 1] = c1; rs[off + 2] = c2; rs[off + 3] = c3;
    __syncthreads();
    hist[off] = c0; hist[off + 1] = c1; hist[off + 2] = c2; hist[off + 3] = c3;
    if (tid == 0) rs[PART] = hi;  // end sentinel
    __syncthreads();
    int total = hi - lo;
    bool ovf = total > STCAP;
    for (int i = lo + tid; i < hi; i += 512) {
        unsigned w = packed[i];
        int pos = atomicAdd(&hist[w >> SRCB], 1);
        unsigned sv = w & ((1u << SRCB) - 1);
        if (!ovf) stage[pos - lo] = sv;
        else srcsorted[pos] = sv;
    }
    __syncthreads();
    if (!ovf)
        for (int j = tid; j < total; j += 512) srcsorted[lo + j] = (int)stage[j];
}

// ---------------- Node-side (atomic-free, thread-per-node) ----------------

__global__ __launch_bounds__(512) void dinvg_kernel(
    const int* __restrict__ runStart, const float* __restrict__ x,
    float* __restrict__ dinv, float* __restrict__ g, int n) {
    int i = blockIdx.x * 512 + threadIdx.x;
    if (i >= n) return;
    int dp = i >> LPBIT, ld = i & (PART - 1);
    int deg = 0;
    #pragma unroll
    for (int b = 0; b < BC; b++) {
        const int* rs = runStart + (size_t)(dp * BC + b) * RSTR + ld;
        deg += rs[1] - rs[0];
    }
    float d = rsqrtf((float)deg + 1.0f);  // +1 self-loop
    dinv[i] = d;
    float2 xv = ((const float2*)x)[i];
    ((float2*)g)[i] = make_float2(xv.x * d, xv.y * d);
}

// thread = node: 4 runs, gather g[src], register acc + fused W1/ReLU/W2.
__global__ __launch_bounds__(512) void agg1_kernel(
    const int* __restrict__ runStart, const int* __restrict__ srcsorted,
    const float* __restrict__ g, const float* __restrict__ dinv,
    const float* __restrict__ W1, const float* __restrict__ b1,
    const float* __restrict__ W2, float* __restrict__ hs2, int n) {
    int i = blockIdx.x * 512 + threadIdx.x;
    if (i >= n) return;
    int dp = i >> LPBIT, ld = i & (PART - 1);
    const float2* gp = (const float2*)g;
    float s0 = 0.0f, s1 = 0.0f;
    #pragma unroll
    for (int b = 0; b < BC; b++) {
        const int* rs = runStart + (size_t)(dp * BC + b) * RSTR + ld;
        int p0 = rs[0], p1 = rs[1];
        int p = p0;
        for (; p + 4 <= p1; p += 4) {
            int a = srcsorted[p], bb = srcsorted[p + 1];
            int c = srcsorted[p + 2], e = srcsorted[p + 3];
            float2 w0 = gp[a], w1 = gp[bb], w2 = gp[c], w3 = gp[e];
            s0 += w0.x + w1.x + w2.x + w3.x;
            s1 += w0.y + w1.y + w2.y + w3.y;
        }
        for (; p < p1; p++) {
            float2 w = gp[srcsorted[p]];
            s0 += w.x;
            s1 += w.y;
        }
    }
    float d = dinv[i];
    float2 gi = gp[i];
    s0 = (s0 + gi.x) * d;
    s1 = (s1 + gi.y) * d;
    float h[8];
    #pragma unroll
    for (int f = 0; f < 8; f++)
        h[f] = fmaxf(s0 * W1[f] + s1 * W1[8 + f] + b1[f], 0.0f);
    float oc[4];
    #pragma unroll
    for (int k = 0; k < 4; k++) {
        float a = 0.0f;
        #pragma unroll
        for (int f = 0; f < 8; f++) a += h[f] * W2[4 * f + k];
        oc[k] = a * d;
    }
    float4 o;
    o.x = oc[0]; o.y = oc[1]; o.z = oc[2]; o.w = oc[3];
    *(float4*)(hs2 + 4 * (size_t)i) = o;
}

// thread = node: 4 runs, gather hs2[src], write final output.
__global__ __launch_bounds__(512) void agg2_kernel(
    const int* __restrict__ runStart, const int* __restrict__ srcsorted,
    const float* __restrict__ hs2, const float* __restrict__ dinv,
    const float* __restrict__ b2, float* __restrict__ out, int n) {
    int i = blockIdx.x * 512 + threadIdx.x;
    if (i >= n) return;
    int dp = i >> LPBIT, ld = i & (PART - 1);
    const float4* hp = (const float4*)hs2;
    float s0 = 0.0f, s1 = 0.0f, s2 = 0.0f, s3 = 0.0f;
    #pragma unroll
    for (int b = 0; b < BC; b++) {
        const int* rs = runStart + (size_t)(dp * BC + b) * RSTR + ld;
        int p0 = rs[0], p1 = rs[1];
        int p = p0;
        for (; p + 4 <= p1; p += 4) {
            int a = srcsorted[p], bb = srcsorted[p + 1];
            int c = srcsorted[p + 2], e = srcsorted[p + 3];
            float4 w0 = hp[a], w1 = hp[bb], w2 = hp[c], w3 = hp[e];
            s0 += w0.x + w1.x + w2.x + w3.x;
            s1 += w0.y + w1.y + w2.y + w3.y;
            s2 += w0.z + w1.z + w2.z + w3.z;
            s3 += w0.w + w1.w + w2.w + w3.w;
        }
        for (; p < p1; p++) {
            float4 w = hp[srcsorted[p]];
            s0 += w.x; s1 += w.y; s2 += w.z; s3 += w.w;
        }
    }
    float d = dinv[i];
    float4 hi2 = hp[i];
    float4 o;
    o.x = d * (s0 + hi2.x) + b2[0];
    o.y = d * (s1 + hi2.y) + b2[1];
    o.z = d * (s2 + hi2.z) + b2[2];
    o.w = d * (s3 + hi2.w) + b2[3];
    *(float4*)(out + 4 * (size_t)i) = o;
}

extern "C" void kernel_launch(void* const* d_in, const int* in_sizes, int n_in,
                              void* d_out, int out_size, void* d_ws, size_t ws_size,
                              hipStream_t stream) {
    const float* x   = (const float*)d_in[0];
    const int*   ei  = (const int*)d_in[1];
    const float* W1  = (const float*)d_in[2];
    const float* b1  = (const float*)d_in[3];
    const float* W2  = (const float*)d_in[4];
    const float* b2  = (const float*)d_in[5];
    float* out = (float*)d_out;

    const int n = in_sizes[0] / 2;  // x is [N,2]
    const int E = in_sizes[1] / 2;  // edge_index is [2,E]
    const int* src = ei;
    const int* dst = ei + E;

    const int P  = (n + PART - 1) >> LPBIT;  // 98
    const int B1 = (E + EPB - 1) / EPB;      // 782

    int* ws = (int*)d_ws;
    int* cursor = ws;                                        // 128
    int* runStart = ws + 128;                                // P*BC*RSTR
    size_t rssz = (((size_t)P * BC * RSTR) + 3) & ~(size_t)3;
    unsigned* packed = (unsigned*)(runStart + rssz);         // P*CAP
    int* srcsorted = (int*)(packed + (size_t)P * CAP);       // P*CAP
    // packed region dead after localC; overlay node buffers (7*nd << P*CAP):
    size_t nd = (size_t)P << LPBIT;                          // 200704
    float* dinv = (float*)packed;                            // nd
    float* g    = dinv + nd;                                 // 2*nd
    float* hs2  = g + 2 * nd;                                // 4*nd

    hipMemsetAsync(cursor, 0, 128 * sizeof(int), stream);

    const int gN = (n + 511) / 512;

    sortA_kernel <<<B1, 512, 0, stream>>>(src, dst, cursor, packed, E, P);
    localC_kernel<<<P * BC, 512, 0, stream>>>(packed, cursor, runStart, srcsorted);
    dinvg_kernel <<<gN, 512, 0, stream>>>(runStart, x, dinv, g, n);
    agg1_kernel  <<<gN, 512, 0, stream>>>(runStart, srcsorted, g, dinv, W1, b1, W2, hs2, n);
    agg2_kernel  <<<gN, 512, 0, stream>>>(runStart, srcsorted, hs2, dinv, b2, out, n);
}